// Round 10
// baseline (491.408 us; speedup 1.0000x reference)
//
#include <hip/hip_runtime.h>

// RNN-T joint: log_softmax(fc2(tanh(fc1(cat(enc,dec))))), fused.
// B=4, M=256, N=128, D=512, C=1024, JOINT=1024.
// ws: heb f32 [1024][512] (he+b1) | hdb bf16 [512][512] | w2p bf16 frag-packed
//
// R10 = R7 (best: 32-row x 1024-col blocks, 8 waves, 2 blocks/CU, swapped
// MFMA, nt stores, XCD swizzle) with the K-loop moved to 32x32x16 MFMA:
// half the MFMA instructions, half the LDS reads, +20% FLOP/cyc, and a
// 2-deep B prefetch in the same 32-VGPR budget (load kt+2 into the slot
// just consumed). k_prep widened 40 -> 112 blocks.

typedef __attribute__((ext_vector_type(8))) __bf16 bf16x8;
typedef __attribute__((ext_vector_type(8))) unsigned short u16x8;
typedef __attribute__((ext_vector_type(4))) float f32x4;
typedef __attribute__((ext_vector_type(16))) float f32x16;

__device__ __forceinline__ float tanh_fast(float x) {
    float e = __expf(2.0f * x);
    return 1.0f - 2.0f / (e + 1.0f);
}
__device__ __forceinline__ float bf2f(unsigned short u) {
    return __builtin_bit_cast(float, (unsigned)u << 16);
}
__device__ __forceinline__ unsigned short f2bf(float f) {
    return __builtin_bit_cast(unsigned short, (__bf16)f);
}

// k_prep-only LDS swizzle
__device__ __forceinline__ int swz(int row, int kbyte) {
    return row * 1024 + (kbyte ^ ((row & 7) << 4));
}

__device__ __forceinline__ bf16x8 cvt8(float4 a, float4 b) {
    bf16x8 r;
    r[0] = (__bf16)a.x; r[1] = (__bf16)a.y; r[2] = (__bf16)a.z; r[3] = (__bf16)a.w;
    r[4] = (__bf16)b.x; r[5] = (__bf16)b.y; r[6] = (__bf16)b.z; r[7] = (__bf16)b.w;
    return r;
}

// ---------------------------------------------------------------------------
// Prep: blocks 0..31  -> heb = enc@w1enc^T + b1 (f32), 32 rows each
//       blocks 32..47 -> hdb = bf16(dec@w1dec^T), 32 rows each
//       blocks 48..111-> w2 -> w2p in 32x32 A-fragment order:
//         region (c32*32 + kt16) [1KB], chunk khalf*32 + (c&31), 8 bf16.
// ---------------------------------------------------------------------------
__global__ __launch_bounds__(512) void k_prep(
    const float* __restrict__ enc, const float* __restrict__ dec,
    const float* __restrict__ w1, const float* __restrict__ b1,
    const float* __restrict__ w2,
    float* __restrict__ heb, unsigned short* __restrict__ hdb,
    unsigned short* __restrict__ w2p)
{
    const int bid = blockIdx.x, tid = threadIdx.x;

    if (bid >= 48) {  // pack w2 -> w2p (32x32 A layout)
        int t = (bid - 48) * 512 + tid;          // 0..32767
        #pragma unroll
        for (int i = 0; i < 2; ++i) {
            int p = t + i * 32768;               // 0..65535 = (c, kchunk8)
            int c = p >> 6, kc = p & 63;
            const float4* s = (const float4*)(w2 + c * 512 + kc * 8);
            float4 a = s[0], bq = s[1];
            u16x8 o;
            o[0] = f2bf(a.x);  o[1] = f2bf(a.y);  o[2] = f2bf(a.z);  o[3] = f2bf(a.w);
            o[4] = f2bf(bq.x); o[5] = f2bf(bq.y); o[6] = f2bf(bq.z); o[7] = f2bf(bq.w);
            int kt16 = kc >> 1, khalf = kc & 1;
            int chunk = ((c >> 5) * 32 + kt16) * 64 + khalf * 32 + (c & 31);
            *(u16x8*)(w2p + chunk * 8) = o;
        }
        return;
    }

    __shared__ uint4 ldsq[2048];           // 32 KB A tile (32 rows x 512 k bf16)
    char* lds = (char*)ldsq;

    const bool ishe = bid < 32;
    const int r0 = (ishe ? bid : bid - 32) * 32;
    const float* src = (ishe ? enc : dec) + r0 * 512;
    const float* wsrc = w1 + (ishe ? 0 : 512);

    const int lane = tid & 63, wid = tid >> 6;
    #pragma unroll
    for (int j = 0; j < 4; j++) {
        int row = wid * 4 + j;
        const float4* p = (const float4*)(src + row * 512 + lane * 8);
        *(bf16x8*)(lds + swz(row, lane * 16)) = cvt8(p[0], p[1]);
    }
    __syncthreads();

    const int lr = lane & 15, lg = lane >> 4;
    f32x4 acc[2][4];
    #pragma unroll
    for (int rt = 0; rt < 2; rt++)
        #pragma unroll
        for (int ct = 0; ct < 4; ct++)
            acc[rt][ct] = f32x4{0.f, 0.f, 0.f, 0.f};

    #pragma unroll 1
    for (int ks = 0; ks < 512; ks += 32) {
        bf16x8 af[2];
        #pragma unroll
        for (int rt = 0; rt < 2; rt++)
            af[rt] = *(const bf16x8*)(lds + swz(rt * 16 + lr, ks * 2 + lg * 16));
        #pragma unroll
        for (int ct = 0; ct < 4; ct++) {
            int col = wid * 64 + ct * 16 + lr;
            const float4* wp = (const float4*)(wsrc + col * 1024 + ks + lg * 8);
            bf16x8 bfr = cvt8(wp[0], wp[1]);
            #pragma unroll
            for (int rt = 0; rt < 2; rt++)
                acc[rt][ct] = __builtin_amdgcn_mfma_f32_16x16x32_bf16(af[rt], bfr, acc[rt][ct], 0, 0, 0);
        }
    }

    if (ishe) {
        float b1v[4];
        #pragma unroll
        for (int ct = 0; ct < 4; ct++) b1v[ct] = b1[wid * 64 + ct * 16 + lr];
        #pragma unroll
        for (int rt = 0; rt < 2; rt++)
            #pragma unroll
            for (int ct = 0; ct < 4; ct++)
                #pragma unroll
                for (int reg = 0; reg < 4; reg++)
                    heb[(r0 + rt * 16 + lg * 4 + reg) * 512 + wid * 64 + ct * 16 + lr] =
                        acc[rt][ct][reg] + b1v[ct];
    } else {
        #pragma unroll
        for (int rt = 0; rt < 2; rt++)
            #pragma unroll
            for (int ct = 0; ct < 4; ct++)
                #pragma unroll
                for (int reg = 0; reg < 4; reg++)
                    hdb[(r0 + rt * 16 + lg * 4 + reg) * 512 + wid * 64 + ct * 16 + lr] =
                        f2bf(acc[rt][ct][reg]);
    }
}

// ---------------------------------------------------------------------------
// Main: block = 32 rows (one (b,m), 32 n's) x 1024 classes, 8 waves.
// 32x32x16 MFMA, swapped (A = w2 classes, B = hid rows):
//   lane holds output row n = lane&31, classes w*128 + ct*32 + 8q + 4*(lane>>5) + r.
// hid LDS: region kt16 (1KB) chunk = lane; B-frag = one ds_read_b128 per kt16.
// B prefetch 2-deep: consume aw[kt&1], then reload same slot with kt+2.
// ---------------------------------------------------------------------------
__global__ __launch_bounds__(512, 4) void k_main(
    const float* __restrict__ heb, const unsigned short* __restrict__ hdb,
    const float* __restrict__ b2, const unsigned short* __restrict__ w2p,
    float* __restrict__ out)
{
    __shared__ uint4 ldsq[2048];          // 32 KB hid tile: 32 kt16-regions x 1KB
    __shared__ float redm[32][8];         // per-wave row max
    __shared__ float reds[32][8];         // per-wave row sum(exp)
    char* lds = (char*)ldsq;

    // XCD-bijective remap (4096 % 8 == 0)
    const int bid = ((blockIdx.x & 7) << 9) | (blockIdx.x >> 3);
    const int tid = threadIdx.x;
    const int bm = bid >> 2, nq = bid & 3;
    const int b = bm >> 8;
    const int lane = tid & 63, w = tid >> 6;
    const int l5 = lane & 31, lh = lane >> 5;

    // ---- stage hid = tanh(heb + hd) bf16 in 32x32 B-frag layout ----
    // wave w covers kt16 = w*4+it; lane: row = l5, khalf = lh.
    {
        const unsigned short* hb = hdb + (size_t)(b * 128 + nq * 32 + l5) * 512 + lh * 8;
        const float* ep = heb + (size_t)bm * 512 + lh * 8;
        #pragma unroll
        for (int it = 0; it < 4; ++it) {
            int kt = w * 4 + it;
            u16x8 hv = *(const u16x8*)(hb + kt * 16);
            float4 e0 = *(const float4*)(ep + kt * 16);
            float4 e1 = *(const float4*)(ep + kt * 16 + 4);
            bf16x8 xo;
            xo[0] = (__bf16)tanh_fast(bf2f(hv[0]) + e0.x);
            xo[1] = (__bf16)tanh_fast(bf2f(hv[1]) + e0.y);
            xo[2] = (__bf16)tanh_fast(bf2f(hv[2]) + e0.z);
            xo[3] = (__bf16)tanh_fast(bf2f(hv[3]) + e0.w);
            xo[4] = (__bf16)tanh_fast(bf2f(hv[4]) + e1.x);
            xo[5] = (__bf16)tanh_fast(bf2f(hv[5]) + e1.y);
            xo[6] = (__bf16)tanh_fast(bf2f(hv[6]) + e1.z);
            xo[7] = (__bf16)tanh_fast(bf2f(hv[7]) + e1.w);
            *(bf16x8*)(lds + (kt * 64 + lane) * 16) = xo;
        }
    }
    __syncthreads();

    // ---- K-loop: w2 (A) from L2 2-deep prefetch; hid (B) from LDS ----
    // A-frag (ct, kt16) at w2p byte ((w*4+ct)*32 + kt16)*1024 + lane*16
    const char* pw = (const char*)w2p + ((size_t)w << 17) + (lane << 4);
    const char* la = lds + (lane << 4);

    f32x16 acc[4];
    #pragma unroll
    for (int ct = 0; ct < 4; ct++)
        #pragma unroll
        for (int r = 0; r < 16; r++)
            acc[ct][r] = 0.f;

    bf16x8 aw[2][4];
    #pragma unroll
    for (int ct = 0; ct < 4; ct++) {
        aw[0][ct] = *(const bf16x8*)(pw + ct * 32768);
        aw[1][ct] = *(const bf16x8*)(pw + ct * 32768 + 1024);
    }
    bf16x8 h0 = *(const bf16x8*)(la);

    #pragma unroll
    for (int kt = 0; kt < 32; ++kt) {
        bf16x8 hn;
        if (kt < 31) hn = *(const bf16x8*)(la + (kt + 1) * 1024);
        __builtin_amdgcn_s_setprio(1);
        #pragma unroll
        for (int ct = 0; ct < 4; ct++)
            acc[ct] = __builtin_amdgcn_mfma_f32_32x32x16_bf16(aw[kt & 1][ct], h0, acc[ct], 0, 0, 0);
        __builtin_amdgcn_s_setprio(0);
        if (kt < 30) {
            #pragma unroll
            for (int ct = 0; ct < 4; ct++)
                aw[kt & 1][ct] = *(const bf16x8*)(pw + ct * 32768 + (kt + 2) * 1024);
        }
        h0 = hn;
    }

    // ---- +b2: acc[ct][q*4+r] <-> class w*128 + ct*32 + 8q + 4*lh + r ----
    #pragma unroll
    for (int ct = 0; ct < 4; ct++)
        #pragma unroll
        for (int q = 0; q < 4; q++) {
            float4 bq = *(const float4*)(b2 + w * 128 + ct * 32 + q * 8 + lh * 4);
            acc[ct][q * 4 + 0] += bq.x; acc[ct][q * 4 + 1] += bq.y;
            acc[ct][q * 4 + 2] += bq.z; acc[ct][q * 4 + 3] += bq.w;
        }

    // ---- row stats: 64 values in-lane (row n = l5), merge lane^32 ----
    float mx = -3.4e38f;
    #pragma unroll
    for (int ct = 0; ct < 4; ct++)
        #pragma unroll
        for (int r = 0; r < 16; r++)
            mx = fmaxf(mx, acc[ct][r]);
    float sv = 0.f;
    #pragma unroll
    for (int ct = 0; ct < 4; ct++)
        #pragma unroll
        for (int r = 0; r < 16; r++)
            sv += __expf(acc[ct][r] - mx);
    {
        float mo = __shfl_xor(mx, 32), so = __shfl_xor(sv, 32);
        float mn = fmaxf(mx, mo);
        sv = sv * __expf(mx - mn) + so * __expf(mo - mn);
        mx = mn;
    }
    if (lh == 0) { redm[l5][w] = mx; reds[l5][w] = sv; }
    __syncthreads();

    // ---- combine 8 wave-partials -> logZ for row l5 ----
    float logZ;
    {
        float4 ma = *(const float4*)&redm[l5][0];
        float4 mb = *(const float4*)&redm[l5][4];
        float4 sa = *(const float4*)&reds[l5][0];
        float4 sb = *(const float4*)&reds[l5][4];
        float M = fmaxf(fmaxf(fmaxf(ma.x, ma.y), fmaxf(ma.z, ma.w)),
                        fmaxf(fmaxf(mb.x, mb.y), fmaxf(mb.z, mb.w)));
        float S = sa.x * __expf(ma.x - M) + sa.y * __expf(ma.y - M)
                + sa.z * __expf(ma.z - M) + sa.w * __expf(ma.w - M)
                + sb.x * __expf(mb.x - M) + sb.y * __expf(mb.y - M)
                + sb.z * __expf(mb.z - M) + sb.w * __expf(mb.w - M);
        logZ = M + __logf(S);
    }

    // ---- nt-store: 16 float4s, row l5, classes w*128 + ct*32 + 8q + 4lh ----
    const size_t rowbase = (size_t)bm * 128 + nq * 32;
    float* orow = out + (rowbase + l5) * 1024 + w * 128 + lh * 4;
    #pragma unroll
    for (int ct = 0; ct < 4; ct++)
        #pragma unroll
        for (int q = 0; q < 4; q++) {
            f32x4 o;
            o[0] = acc[ct][q * 4 + 0] - logZ;
            o[1] = acc[ct][q * 4 + 1] - logZ;
            o[2] = acc[ct][q * 4 + 2] - logZ;
            o[3] = acc[ct][q * 4 + 3] - logZ;
            __builtin_nontemporal_store(o, (f32x4*)(orow + ct * 32 + q * 8));
        }
}

extern "C" void kernel_launch(void* const* d_in, const int* in_sizes, int n_in,
                              void* d_out, int out_size, void* d_ws, size_t ws_size,
                              hipStream_t stream) {
    const float* enc = (const float*)d_in[0];
    const float* dec = (const float*)d_in[1];
    const float* w1  = (const float*)d_in[2];
    const float* b1  = (const float*)d_in[3];
    const float* w2  = (const float*)d_in[4];
    const float* b2  = (const float*)d_in[5];

    float* heb = (float*)d_ws;                                   // 2 MB
    unsigned short* hdb = (unsigned short*)(heb + 1024 * 512);   // 0.5 MB
    unsigned short* w2p = hdb + 512 * 512;                       // 1 MB

    k_prep<<<112, 512, 0, stream>>>(enc, dec, w1, b1, w2, heb, hdb, w2p);
    k_main<<<4096, 512, 0, stream>>>(heb, hdb, b2, w2p, (float*)d_out);
}

// Round 11
// 288.364 us; speedup vs baseline: 1.7041x; 1.7041x over previous
//
#include <hip/hip_runtime.h>

// RNN-T joint: log_softmax(fc2(tanh(fc1(cat(enc,dec))))), fused.
// B=4, M=256, N=128, D=512, C=1024, JOINT=1024.
// ws: heb f32 [1024][512] (he+b1) | hdb bf16 [512][512] | w2p bf16 frag-packed
//
// R11 = R10 (32x32x16 K-loop, 2-deep B prefetch -> FETCH 7MB, proven) with the
// store epilogue fixed: R10's 32x32 C-layout gave only 2 lanes/row -> 32B
// partial-line nt stores -> WRITE_SIZE doubled (1.08GB). Now each wave
// transposes its 32x32 ct-tile through its OWN 4KB LDS region (dead hid
// buffer, no barrier; XOR-swizzled) and emits full-64B-line nt stores.

typedef __attribute__((ext_vector_type(8))) __bf16 bf16x8;
typedef __attribute__((ext_vector_type(8))) unsigned short u16x8;
typedef __attribute__((ext_vector_type(4))) float f32x4;
typedef __attribute__((ext_vector_type(16))) float f32x16;

__device__ __forceinline__ float tanh_fast(float x) {
    float e = __expf(2.0f * x);
    return 1.0f - 2.0f / (e + 1.0f);
}
__device__ __forceinline__ float bf2f(unsigned short u) {
    return __builtin_bit_cast(float, (unsigned)u << 16);
}
__device__ __forceinline__ unsigned short f2bf(float f) {
    return __builtin_bit_cast(unsigned short, (__bf16)f);
}

// k_prep-only LDS swizzle
__device__ __forceinline__ int swz(int row, int kbyte) {
    return row * 1024 + (kbyte ^ ((row & 7) << 4));
}

__device__ __forceinline__ bf16x8 cvt8(float4 a, float4 b) {
    bf16x8 r;
    r[0] = (__bf16)a.x; r[1] = (__bf16)a.y; r[2] = (__bf16)a.z; r[3] = (__bf16)a.w;
    r[4] = (__bf16)b.x; r[5] = (__bf16)b.y; r[6] = (__bf16)b.z; r[7] = (__bf16)b.w;
    return r;
}

// ---------------------------------------------------------------------------
// Prep (validated R10): blocks 0..31 -> heb = enc@w1enc^T + b1 (f32, 32 rows),
// 32..47 -> hdb = bf16(dec@w1dec^T), 48..111 -> w2 -> w2p in 32x32 A-frag
// order: chunk = ((c>>5)*32 + kt16)*64 + khalf*32 + (c&31), 8 bf16 each.
// ---------------------------------------------------------------------------
__global__ __launch_bounds__(512) void k_prep(
    const float* __restrict__ enc, const float* __restrict__ dec,
    const float* __restrict__ w1, const float* __restrict__ b1,
    const float* __restrict__ w2,
    float* __restrict__ heb, unsigned short* __restrict__ hdb,
    unsigned short* __restrict__ w2p)
{
    const int bid = blockIdx.x, tid = threadIdx.x;

    if (bid >= 48) {  // pack w2 -> w2p (32x32 A layout)
        int t = (bid - 48) * 512 + tid;          // 0..32767
        #pragma unroll
        for (int i = 0; i < 2; ++i) {
            int p = t + i * 32768;               // 0..65535 = (c, kchunk8)
            int c = p >> 6, kc = p & 63;
            const float4* s = (const float4*)(w2 + c * 512 + kc * 8);
            float4 a = s[0], bq = s[1];
            u16x8 o;
            o[0] = f2bf(a.x);  o[1] = f2bf(a.y);  o[2] = f2bf(a.z);  o[3] = f2bf(a.w);
            o[4] = f2bf(bq.x); o[5] = f2bf(bq.y); o[6] = f2bf(bq.z); o[7] = f2bf(bq.w);
            int kt16 = kc >> 1, khalf = kc & 1;
            int chunk = ((c >> 5) * 32 + kt16) * 64 + khalf * 32 + (c & 31);
            *(u16x8*)(w2p + chunk * 8) = o;
        }
        return;
    }

    __shared__ uint4 ldsq[2048];           // 32 KB A tile (32 rows x 512 k bf16)
    char* lds = (char*)ldsq;

    const bool ishe = bid < 32;
    const int r0 = (ishe ? bid : bid - 32) * 32;
    const float* src = (ishe ? enc : dec) + r0 * 512;
    const float* wsrc = w1 + (ishe ? 0 : 512);

    const int lane = tid & 63, wid = tid >> 6;
    #pragma unroll
    for (int j = 0; j < 4; j++) {
        int row = wid * 4 + j;
        const float4* p = (const float4*)(src + row * 512 + lane * 8);
        *(bf16x8*)(lds + swz(row, lane * 16)) = cvt8(p[0], p[1]);
    }
    __syncthreads();

    const int lr = lane & 15, lg = lane >> 4;
    f32x4 acc[2][4];
    #pragma unroll
    for (int rt = 0; rt < 2; rt++)
        #pragma unroll
        for (int ct = 0; ct < 4; ct++)
            acc[rt][ct] = f32x4{0.f, 0.f, 0.f, 0.f};

    #pragma unroll 1
    for (int ks = 0; ks < 512; ks += 32) {
        bf16x8 af[2];
        #pragma unroll
        for (int rt = 0; rt < 2; rt++)
            af[rt] = *(const bf16x8*)(lds + swz(rt * 16 + lr, ks * 2 + lg * 16));
        #pragma unroll
        for (int ct = 0; ct < 4; ct++) {
            int col = wid * 64 + ct * 16 + lr;
            const float4* wp = (const float4*)(wsrc + col * 1024 + ks + lg * 8);
            bf16x8 bfr = cvt8(wp[0], wp[1]);
            #pragma unroll
            for (int rt = 0; rt < 2; rt++)
                acc[rt][ct] = __builtin_amdgcn_mfma_f32_16x16x32_bf16(af[rt], bfr, acc[rt][ct], 0, 0, 0);
        }
    }

    if (ishe) {
        float b1v[4];
        #pragma unroll
        for (int ct = 0; ct < 4; ct++) b1v[ct] = b1[wid * 64 + ct * 16 + lr];
        #pragma unroll
        for (int rt = 0; rt < 2; rt++)
            #pragma unroll
            for (int ct = 0; ct < 4; ct++)
                #pragma unroll
                for (int reg = 0; reg < 4; reg++)
                    heb[(r0 + rt * 16 + lg * 4 + reg) * 512 + wid * 64 + ct * 16 + lr] =
                        acc[rt][ct][reg] + b1v[ct];
    } else {
        #pragma unroll
        for (int rt = 0; rt < 2; rt++)
            #pragma unroll
            for (int ct = 0; ct < 4; ct++)
                #pragma unroll
                for (int reg = 0; reg < 4; reg++)
                    hdb[(r0 + rt * 16 + lg * 4 + reg) * 512 + wid * 64 + ct * 16 + lr] =
                        f2bf(acc[rt][ct][reg]);
    }
}

// ---------------------------------------------------------------------------
// Main: block = 32 rows (one (b,m), 32 n's) x 1024 classes, 8 waves.
// 32x32x16 MFMA, swapped (A = w2 classes, B = hid rows):
//   lane holds output row n = lane&31, classes w*128 + ct*32 + 8q + 4*(lane>>5) + r.
// B prefetch 2-deep (reload just-consumed slot with kt+2). Store epilogue:
// per-wave LDS transpose (own 4KB region, no barrier) -> full-line nt stores.
// ---------------------------------------------------------------------------
__global__ __launch_bounds__(512, 4) void k_main(
    const float* __restrict__ heb, const unsigned short* __restrict__ hdb,
    const float* __restrict__ b2, const unsigned short* __restrict__ w2p,
    float* __restrict__ out)
{
    __shared__ uint4 ldsq[2048];          // 32 KB: hid tile, then transpose buf
    __shared__ float redm[32][8];         // per-wave row max
    __shared__ float reds[32][8];         // per-wave row sum(exp)
    char* lds = (char*)ldsq;

    // XCD-bijective remap (4096 % 8 == 0)
    const int bid = ((blockIdx.x & 7) << 9) | (blockIdx.x >> 3);
    const int tid = threadIdx.x;
    const int bm = bid >> 2, nq = bid & 3;
    const int b = bm >> 8;
    const int lane = tid & 63, w = tid >> 6;
    const int l5 = lane & 31, lh = lane >> 5;

    // ---- stage hid = tanh(heb + hd) bf16 in 32x32 B-frag layout ----
    // wave w covers kt16 = w*4+it; lane: row = l5, khalf = lh.
    {
        const unsigned short* hb = hdb + (size_t)(b * 128 + nq * 32 + l5) * 512 + lh * 8;
        const float* ep = heb + (size_t)bm * 512 + lh * 8;
        #pragma unroll
        for (int it = 0; it < 4; ++it) {
            int kt = w * 4 + it;
            u16x8 hv = *(const u16x8*)(hb + kt * 16);
            float4 e0 = *(const float4*)(ep + kt * 16);
            float4 e1 = *(const float4*)(ep + kt * 16 + 4);
            bf16x8 xo;
            xo[0] = (__bf16)tanh_fast(bf2f(hv[0]) + e0.x);
            xo[1] = (__bf16)tanh_fast(bf2f(hv[1]) + e0.y);
            xo[2] = (__bf16)tanh_fast(bf2f(hv[2]) + e0.z);
            xo[3] = (__bf16)tanh_fast(bf2f(hv[3]) + e0.w);
            xo[4] = (__bf16)tanh_fast(bf2f(hv[4]) + e1.x);
            xo[5] = (__bf16)tanh_fast(bf2f(hv[5]) + e1.y);
            xo[6] = (__bf16)tanh_fast(bf2f(hv[6]) + e1.z);
            xo[7] = (__bf16)tanh_fast(bf2f(hv[7]) + e1.w);
            *(bf16x8*)(lds + (kt * 64 + lane) * 16) = xo;
        }
    }
    __syncthreads();

    // ---- K-loop: w2 (A) from L2, 2-deep slot-reuse prefetch; hid (B) LDS ----
    const char* pw = (const char*)w2p + ((size_t)w << 17) + (lane << 4);
    const char* la = lds + (lane << 4);

    f32x16 acc[4];
    #pragma unroll
    for (int ct = 0; ct < 4; ct++)
        #pragma unroll
        for (int r = 0; r < 16; r++)
            acc[ct][r] = 0.f;

    bf16x8 aw[2][4];
    #pragma unroll
    for (int ct = 0; ct < 4; ct++) {
        aw[0][ct] = *(const bf16x8*)(pw + ct * 32768);
        aw[1][ct] = *(const bf16x8*)(pw + ct * 32768 + 1024);
    }
    bf16x8 h0 = *(const bf16x8*)(la);

    #pragma unroll
    for (int kt = 0; kt < 32; ++kt) {
        bf16x8 hn;
        if (kt < 31) hn = *(const bf16x8*)(la + (kt + 1) * 1024);
        __builtin_amdgcn_s_setprio(1);
        #pragma unroll
        for (int ct = 0; ct < 4; ct++)
            acc[ct] = __builtin_amdgcn_mfma_f32_32x32x16_bf16(aw[kt & 1][ct], h0, acc[ct], 0, 0, 0);
        __builtin_amdgcn_s_setprio(0);
        if (kt < 30) {
            #pragma unroll
            for (int ct = 0; ct < 4; ct++)
                aw[kt & 1][ct] = *(const bf16x8*)(pw + ct * 32768 + (kt + 2) * 1024);
        }
        h0 = hn;
    }

    // ---- +b2: acc[ct][q*4+r] <-> class w*128 + ct*32 + 8q + 4*lh + r ----
    #pragma unroll
    for (int ct = 0; ct < 4; ct++)
        #pragma unroll
        for (int q = 0; q < 4; q++) {
            float4 bq = *(const float4*)(b2 + w * 128 + ct * 32 + q * 8 + lh * 4);
            acc[ct][q * 4 + 0] += bq.x; acc[ct][q * 4 + 1] += bq.y;
            acc[ct][q * 4 + 2] += bq.z; acc[ct][q * 4 + 3] += bq.w;
        }

    // ---- row stats: 64 values in-lane (row n = l5), merge lane^32 ----
    float mx = -3.4e38f;
    #pragma unroll
    for (int ct = 0; ct < 4; ct++)
        #pragma unroll
        for (int r = 0; r < 16; r++)
            mx = fmaxf(mx, acc[ct][r]);
    float sv = 0.f;
    #pragma unroll
    for (int ct = 0; ct < 4; ct++)
        #pragma unroll
        for (int r = 0; r < 16; r++)
            sv += __expf(acc[ct][r] - mx);
    {
        float mo = __shfl_xor(mx, 32), so = __shfl_xor(sv, 32);
        float mn = fmaxf(mx, mo);
        sv = sv * __expf(mx - mn) + so * __expf(mo - mn);
        mx = mn;
    }
    if (lh == 0) { redm[l5][w] = mx; reds[l5][w] = sv; }
    __syncthreads();   // after this, hid LDS is dead everywhere -> reuse

    // ---- combine 8 wave-partials -> logZ for row l5 ----
    float logZ;
    {
        float4 ma = *(const float4*)&redm[l5][0];
        float4 mb = *(const float4*)&redm[l5][4];
        float4 sa = *(const float4*)&reds[l5][0];
        float4 sb = *(const float4*)&reds[l5][4];
        float M = fmaxf(fmaxf(fmaxf(ma.x, ma.y), fmaxf(ma.z, ma.w)),
                        fmaxf(fmaxf(mb.x, mb.y), fmaxf(mb.z, mb.w)));
        float S = sa.x * __expf(ma.x - M) + sa.y * __expf(ma.y - M)
                + sa.z * __expf(ma.z - M) + sa.w * __expf(ma.w - M)
                + sb.x * __expf(mb.x - M) + sb.y * __expf(mb.y - M)
                + sb.z * __expf(mb.z - M) + sb.w * __expf(mb.w - M);
        logZ = M + __logf(S);
    }

    // ---- store epilogue: per-wave LDS transpose -> full-line nt stores ----
    // Wave-private 4KB region: [32 rows][32 floats], byte col XOR (row&7)<<4.
    // No barrier: each wave reads only its own region (lgkmcnt orders it).
    char* myr = lds + w * 4096;
    const size_t rowbase = (size_t)bm * 128 + nq * 32;
    const int rr = lane >> 2, c4 = lane & 3;
    #pragma unroll
    for (int ct = 0; ct < 4; ct++) {
        // write: lane (l5, lh) holds floats 8q+4lh+0..3 of row l5
        #pragma unroll
        for (int q = 0; q < 4; q++) {
            f32x4 o;
            o[0] = acc[ct][q * 4 + 0] - logZ;
            o[1] = acc[ct][q * 4 + 1] - logZ;
            o[2] = acc[ct][q * 4 + 2] - logZ;
            o[3] = acc[ct][q * 4 + 3] - logZ;
            *(f32x4*)(myr + l5 * 128 + ((q * 32 + lh * 16) ^ ((l5 & 7) << 4))) = o;
        }
        // read transposed + nt-store: 4-lane cluster c4 covers 64B of row
        #pragma unroll
        for (int rh = 0; rh < 2; rh++)
            #pragma unroll
            for (int chv = 0; chv < 2; chv++) {
                int row = rh * 16 + rr;
                f32x4 v = *(const f32x4*)(myr + row * 128 +
                                          ((chv * 64 + c4 * 16) ^ ((row & 7) << 4)));
                __builtin_nontemporal_store(v,
                    (f32x4*)(out + (rowbase + row) * 1024 + w * 128 + ct * 32 +
                             chv * 16 + c4 * 4));
            }
    }
}

extern "C" void kernel_launch(void* const* d_in, const int* in_sizes, int n_in,
                              void* d_out, int out_size, void* d_ws, size_t ws_size,
                              hipStream_t stream) {
    const float* enc = (const float*)d_in[0];
    const float* dec = (const float*)d_in[1];
    const float* w1  = (const float*)d_in[2];
    const float* b1  = (const float*)d_in[3];
    const float* w2  = (const float*)d_in[4];
    const float* b2  = (const float*)d_in[5];

    float* heb = (float*)d_ws;                                   // 2 MB
    unsigned short* hdb = (unsigned short*)(heb + 1024 * 512);   // 0.5 MB
    unsigned short* w2p = hdb + 512 * 512;                       // 1 MB

    k_prep<<<112, 512, 0, stream>>>(enc, dec, w1, b1, w2, heb, hdb, w2p);
    k_main<<<4096, 512, 0, stream>>>(heb, hdb, b2, w2p, (float*)d_out);
}

// Round 12
// 223.172 us; speedup vs baseline: 2.2019x; 1.2921x over previous
//
#include <hip/hip_runtime.h>

// RNN-T joint: log_softmax(fc2(tanh(fc1(cat(enc,dec))))), fused.
// B=4, M=256, N=128, D=512, C=1024, JOINT=1024.
// ws: heb f32 [1024][512] (he+b1) | hdb bf16 [512][512] | w2p i8 packed 512KB | scF f32[1024]
//
// R12 = R11 structure (32-row x 1024-col blocks, 8 waves, swapped MFMA,
// 2-deep B prefetch, transpose epilogue, nt stores, XCD swizzle) with the
// GEMM moved to INT8 (mfma_i32_32x32x32_i8, K=32):
//  - hid = tanh in [-1,1] -> i8 with fixed scale 127 (err ~ bf16-level)
//  - w2 per-class scale s_c = rowmax -> i8; logit = acc * s_c/16129 + b2
//  - B-feed halves (512KB), MFMA count halves (64/wave), LDS reads halve.

typedef __attribute__((ext_vector_type(8))) __bf16 bf16x8;
typedef __attribute__((ext_vector_type(8))) unsigned short u16x8;
typedef __attribute__((ext_vector_type(4))) float f32x4;
typedef __attribute__((ext_vector_type(4))) int i32x4;
typedef __attribute__((ext_vector_type(16))) int i32x16;

__device__ __forceinline__ float tanh_fast(float x) {
    float e = __expf(2.0f * x);
    return 1.0f - 2.0f / (e + 1.0f);
}
__device__ __forceinline__ float bf2f(unsigned short u) {
    return __builtin_bit_cast(float, (unsigned)u << 16);
}
__device__ __forceinline__ unsigned short f2bf(float f) {
    return __builtin_bit_cast(unsigned short, (__bf16)f);
}
// quantize 4 floats (prescale s) -> packed i8x4
__device__ __forceinline__ int pack4(float a, float b, float c, float d, float s) {
    int q0 = __float2int_rn(a * s) & 255;
    int q1 = __float2int_rn(b * s) & 255;
    int q2 = __float2int_rn(c * s) & 255;
    int q3 = __float2int_rn(d * s) & 255;
    return q0 | (q1 << 8) | (q2 << 16) | (q3 << 24);
}

// k_prep-only LDS swizzle
__device__ __forceinline__ int swz(int row, int kbyte) {
    return row * 1024 + (kbyte ^ ((row & 7) << 4));
}

__device__ __forceinline__ bf16x8 cvt8(float4 a, float4 b) {
    bf16x8 r;
    r[0] = (__bf16)a.x; r[1] = (__bf16)a.y; r[2] = (__bf16)a.z; r[3] = (__bf16)a.w;
    r[4] = (__bf16)b.x; r[5] = (__bf16)b.y; r[6] = (__bf16)b.z; r[7] = (__bf16)b.w;
    return r;
}

// ---------------------------------------------------------------------------
// Prep: blocks 0..31  -> heb = enc@w1enc^T + b1 (f32), 32 rows each
//       blocks 32..47 -> hdb = bf16(dec@w1dec^T), 32 rows each
//       blocks 48..63 -> w2 quantize+pack: one wave per 8 classes.
//   w2p chunk for (class c, kt32 t): byte ((c>>5)*16 + t)*1024 + lane_c*16,
//   lane_c = lh*32 + (c&31); 16 i8 = k t*32 + lh*16 + 0..15. scF[c]=s_c/16129.
// ---------------------------------------------------------------------------
__global__ __launch_bounds__(512) void k_prep(
    const float* __restrict__ enc, const float* __restrict__ dec,
    const float* __restrict__ w1, const float* __restrict__ b1,
    const float* __restrict__ w2,
    float* __restrict__ heb, unsigned short* __restrict__ hdb,
    char* __restrict__ w2p, float* __restrict__ scF)
{
    const int bid = blockIdx.x, tid = threadIdx.x;
    const int lane = tid & 63, wid = tid >> 6;

    if (bid >= 48) {  // quantize + pack w2 -> w2p (i8), write scF
        int W = (bid - 48) * 8 + wid;            // 0..127
        #pragma unroll
        for (int j = 0; j < 8; ++j) {
            int c = W * 8 + j;
            const float4* s = (const float4*)(w2 + c * 512 + lane * 8);
            float4 a = s[0], bq = s[1];
            float m = fmaxf(fmaxf(fabsf(a.x), fabsf(a.y)), fmaxf(fabsf(a.z), fabsf(a.w)));
            m = fmaxf(m, fmaxf(fmaxf(fabsf(bq.x), fabsf(bq.y)),
                               fmaxf(fabsf(bq.z), fabsf(bq.w))));
            #pragma unroll
            for (int d = 1; d < 64; d <<= 1) m = fmaxf(m, __shfl_xor(m, d));
            float r = 127.f / m;
            int d0 = pack4(a.x, a.y, a.z, a.w, r);
            int d1 = pack4(bq.x, bq.y, bq.z, bq.w, r);
            int t = lane >> 2, lhc = (lane >> 1) & 1, off = lane & 1;
            char* dst = w2p + ((size_t)((c >> 5) * 16 + t)) * 1024
                        + lhc * 512 + (c & 31) * 16 + off * 8;
            *(unsigned long long*)dst =
                (unsigned)d0 | ((unsigned long long)(unsigned)d1 << 32);
            if (lane == 0) scF[c] = m / 16129.f;   // 127*127
        }
        return;
    }

    __shared__ uint4 ldsq[2048];           // 32 KB A tile (32 rows x 512 k bf16)
    char* lds = (char*)ldsq;

    const bool ishe = bid < 32;
    const int r0 = (ishe ? bid : bid - 32) * 32;
    const float* src = (ishe ? enc : dec) + r0 * 512;
    const float* wsrc = w1 + (ishe ? 0 : 512);

    #pragma unroll
    for (int j = 0; j < 4; j++) {
        int row = wid * 4 + j;
        const float4* p = (const float4*)(src + row * 512 + lane * 8);
        *(bf16x8*)(lds + swz(row, lane * 16)) = cvt8(p[0], p[1]);
    }
    __syncthreads();

    const int lr = lane & 15, lg = lane >> 4;
    f32x4 acc[2][4];
    #pragma unroll
    for (int rt = 0; rt < 2; rt++)
        #pragma unroll
        for (int ct = 0; ct < 4; ct++)
            acc[rt][ct] = f32x4{0.f, 0.f, 0.f, 0.f};

    #pragma unroll 1
    for (int ks = 0; ks < 512; ks += 32) {
        bf16x8 af[2];
        #pragma unroll
        for (int rt = 0; rt < 2; rt++)
            af[rt] = *(const bf16x8*)(lds + swz(rt * 16 + lr, ks * 2 + lg * 16));
        #pragma unroll
        for (int ct = 0; ct < 4; ct++) {
            int col = wid * 64 + ct * 16 + lr;
            const float4* wp = (const float4*)(wsrc + col * 1024 + ks + lg * 8);
            bf16x8 bfr = cvt8(wp[0], wp[1]);
            #pragma unroll
            for (int rt = 0; rt < 2; rt++)
                acc[rt][ct] = __builtin_amdgcn_mfma_f32_16x16x32_bf16(af[rt], bfr, acc[rt][ct], 0, 0, 0);
        }
    }

    if (ishe) {
        float b1v[4];
        #pragma unroll
        for (int ct = 0; ct < 4; ct++) b1v[ct] = b1[wid * 64 + ct * 16 + lr];
        #pragma unroll
        for (int rt = 0; rt < 2; rt++)
            #pragma unroll
            for (int ct = 0; ct < 4; ct++)
                #pragma unroll
                for (int reg = 0; reg < 4; reg++)
                    heb[(r0 + rt * 16 + lg * 4 + reg) * 512 + wid * 64 + ct * 16 + lr] =
                        acc[rt][ct][reg] + b1v[ct];
    } else {
        #pragma unroll
        for (int rt = 0; rt < 2; rt++)
            #pragma unroll
            for (int ct = 0; ct < 4; ct++)
                #pragma unroll
                for (int reg = 0; reg < 4; reg++)
                    hdb[(r0 + rt * 16 + lg * 4 + reg) * 512 + wid * 64 + ct * 16 + lr] =
                        f2bf(acc[rt][ct][reg]);
    }
}

// ---------------------------------------------------------------------------
// Main: block = 32 rows (one (b,m), 32 n's) x 1024 classes, 8 waves.
// mfma_i32_32x32x32_i8, swapped (A = w2 classes, B = hid rows):
//   lane holds row n = lane&31; classes w*128 + ct*32 + 8q + 4*(lane>>5) + i.
// 16 kt32 steps; A 2-deep slot-reuse prefetch from L2 (512KB w2p).
// Epilogue: x = acc*scF[c] + b2[c] written back into acc as f32 bits;
// softmax; per-wave LDS transpose; full-line nt stores.
// ---------------------------------------------------------------------------
__global__ __launch_bounds__(512, 4) void k_main(
    const float* __restrict__ heb, const unsigned short* __restrict__ hdb,
    const float* __restrict__ b2, const char* __restrict__ w2p,
    const float* __restrict__ scF, float* __restrict__ out)
{
    __shared__ uint4 ldsq[2048];          // 32 KB: hid_q (16KB) then transpose
    __shared__ float redm[32][8];
    __shared__ float reds[32][8];
    char* lds = (char*)ldsq;

    // XCD-bijective remap (4096 % 8 == 0)
    const int bid = ((blockIdx.x & 7) << 9) | (blockIdx.x >> 3);
    const int tid = threadIdx.x;
    const int bm = bid >> 2, nq = bid & 3;
    const int b = bm >> 8;
    const int lane = tid & 63, w = tid >> 6;
    const int l5 = lane & 31, lh = lane >> 5;

    // ---- stage hid_q = i8(tanh(heb + hd) * 127), B-frag layout ----
    // wave w covers kt32 regions t = 2w, 2w+1; lane: row l5, k = t*32+lh*16+0..15
    {
        const unsigned short* hb = hdb + (size_t)(b * 128 + nq * 32 + l5) * 512;
        const float* ep = heb + (size_t)bm * 512;
        #pragma unroll
        for (int it = 0; it < 2; ++it) {
            int t = w * 2 + it;
            int k0 = t * 32 + lh * 16;
            u16x8 hv0 = *(const u16x8*)(hb + k0);
            u16x8 hv1 = *(const u16x8*)(hb + k0 + 8);
            float4 e0 = *(const float4*)(ep + k0);
            float4 e1 = *(const float4*)(ep + k0 + 4);
            float4 e2 = *(const float4*)(ep + k0 + 8);
            float4 e3 = *(const float4*)(ep + k0 + 12);
            i32x4 o;
            o[0] = pack4(tanh_fast(bf2f(hv0[0]) + e0.x), tanh_fast(bf2f(hv0[1]) + e0.y),
                         tanh_fast(bf2f(hv0[2]) + e0.z), tanh_fast(bf2f(hv0[3]) + e0.w), 127.f);
            o[1] = pack4(tanh_fast(bf2f(hv0[4]) + e1.x), tanh_fast(bf2f(hv0[5]) + e1.y),
                         tanh_fast(bf2f(hv0[6]) + e1.z), tanh_fast(bf2f(hv0[7]) + e1.w), 127.f);
            o[2] = pack4(tanh_fast(bf2f(hv1[0]) + e2.x), tanh_fast(bf2f(hv1[1]) + e2.y),
                         tanh_fast(bf2f(hv1[2]) + e2.z), tanh_fast(bf2f(hv1[3]) + e2.w), 127.f);
            o[3] = pack4(tanh_fast(bf2f(hv1[4]) + e3.x), tanh_fast(bf2f(hv1[5]) + e3.y),
                         tanh_fast(bf2f(hv1[6]) + e3.z), tanh_fast(bf2f(hv1[7]) + e3.w), 127.f);
            *(i32x4*)(lds + t * 1024 + lane * 16) = o;
        }
    }
    __syncthreads();

    // ---- K-loop: w2 (A) from L2, 2-deep slot-reuse prefetch; hid_q (B) LDS ----
    // A-chunk (ctile = w*4+ct, t) at byte (ctile*16 + t)*1024 + lane*16
    const char* pw = w2p + ((size_t)w << 16) + (lane << 4);
    const char* la = lds + (lane << 4);

    i32x16 acc[4];
    #pragma unroll
    for (int ct = 0; ct < 4; ct++)
        #pragma unroll
        for (int r = 0; r < 16; r++)
            acc[ct][r] = 0;

    i32x4 aw[2][4];
    #pragma unroll
    for (int ct = 0; ct < 4; ct++) {
        aw[0][ct] = *(const i32x4*)(pw + ct * 16384);
        aw[1][ct] = *(const i32x4*)(pw + ct * 16384 + 1024);
    }
    i32x4 h0 = *(const i32x4*)(la);

    #pragma unroll
    for (int kt = 0; kt < 16; ++kt) {
        i32x4 hn;
        if (kt < 15) hn = *(const i32x4*)(la + (kt + 1) * 1024);
        __builtin_amdgcn_s_setprio(1);
        #pragma unroll
        for (int ct = 0; ct < 4; ct++)
            acc[ct] = __builtin_amdgcn_mfma_i32_32x32x32_i8(aw[kt & 1][ct], h0, acc[ct], 0, 0, 0);
        __builtin_amdgcn_s_setprio(0);
        if (kt < 14) {
            #pragma unroll
            for (int ct = 0; ct < 4; ct++)
                aw[kt & 1][ct] = *(const i32x4*)(pw + ct * 16384 + (kt + 2) * 1024);
        }
        h0 = hn;
    }

    // ---- dequant + b2, f32 bits written back in place ----
    // acc[ct][q*4+i] <-> class w*128 + ct*32 + 8q + 4*lh + i
    #pragma unroll
    for (int ct = 0; ct < 4; ct++)
        #pragma unroll
        for (int q = 0; q < 4; q++) {
            const int base = w * 128 + ct * 32 + q * 8 + lh * 4;
            float4 sc4 = *(const float4*)(scF + base);
            float4 b24 = *(const float4*)(b2 + base);
            acc[ct][q * 4 + 0] = __float_as_int((float)acc[ct][q * 4 + 0] * sc4.x + b24.x);
            acc[ct][q * 4 + 1] = __float_as_int((float)acc[ct][q * 4 + 1] * sc4.y + b24.y);
            acc[ct][q * 4 + 2] = __float_as_int((float)acc[ct][q * 4 + 2] * sc4.z + b24.z);
            acc[ct][q * 4 + 3] = __float_as_int((float)acc[ct][q * 4 + 3] * sc4.w + b24.w);
        }

    // ---- row stats: 64 values in-lane (row n = l5), merge lane^32 ----
    float mx = -3.4e38f;
    #pragma unroll
    for (int ct = 0; ct < 4; ct++)
        #pragma unroll
        for (int r = 0; r < 16; r++)
            mx = fmaxf(mx, __int_as_float(acc[ct][r]));
    float sv = 0.f;
    #pragma unroll
    for (int ct = 0; ct < 4; ct++)
        #pragma unroll
        for (int r = 0; r < 16; r++)
            sv += __expf(__int_as_float(acc[ct][r]) - mx);
    {
        float mo = __shfl_xor(mx, 32), so = __shfl_xor(sv, 32);
        float mn = fmaxf(mx, mo);
        sv = sv * __expf(mx - mn) + so * __expf(mo - mn);
        mx = mn;
    }
    if (lh == 0) { redm[l5][w] = mx; reds[l5][w] = sv; }
    __syncthreads();   // hid LDS dead after this -> reuse for transpose

    float logZ;
    {
        float4 ma = *(const float4*)&redm[l5][0];
        float4 mb = *(const float4*)&redm[l5][4];
        float4 sa = *(const float4*)&reds[l5][0];
        float4 sb = *(const float4*)&reds[l5][4];
        float M = fmaxf(fmaxf(fmaxf(ma.x, ma.y), fmaxf(ma.z, ma.w)),
                        fmaxf(fmaxf(mb.x, mb.y), fmaxf(mb.z, mb.w)));
        float S = sa.x * __expf(ma.x - M) + sa.y * __expf(ma.y - M)
                + sa.z * __expf(ma.z - M) + sa.w * __expf(ma.w - M)
                + sb.x * __expf(mb.x - M) + sb.y * __expf(mb.y - M)
                + sb.z * __expf(mb.z - M) + sb.w * __expf(mb.w - M);
        logZ = M + __logf(S);
    }

    // ---- store epilogue: per-wave LDS transpose -> full-line nt stores ----
    char* myr = lds + w * 4096;
    const size_t rowbase = (size_t)bm * 128 + nq * 32;
    const int rr = lane >> 2, c4 = lane & 3;
    #pragma unroll
    for (int ct = 0; ct < 4; ct++) {
        #pragma unroll
        for (int q = 0; q < 4; q++) {
            f32x4 o;
            o[0] = __int_as_float(acc[ct][q * 4 + 0]) - logZ;
            o[1] = __int_as_float(acc[ct][q * 4 + 1]) - logZ;
            o[2] = __int_as_float(acc[ct][q * 4 + 2]) - logZ;
            o[3] = __int_as_float(acc[ct][q * 4 + 3]) - logZ;
            *(f32x4*)(myr + l5 * 128 + ((q * 32 + lh * 16) ^ ((l5 & 7) << 4))) = o;
        }
        #pragma unroll
        for (int rh = 0; rh < 2; rh++)
            #pragma unroll
            for (int chv = 0; chv < 2; chv++) {
                int row = rh * 16 + rr;
                f32x4 v = *(const f32x4*)(myr + row * 128 +
                                          ((chv * 64 + c4 * 16) ^ ((row & 7) << 4)));
                __builtin_nontemporal_store(v,
                    (f32x4*)(out + (rowbase + row) * 1024 + w * 128 + ct * 32 +
                             chv * 16 + c4 * 4));
            }
    }
}

extern "C" void kernel_launch(void* const* d_in, const int* in_sizes, int n_in,
                              void* d_out, int out_size, void* d_ws, size_t ws_size,
                              hipStream_t stream) {
    const float* enc = (const float*)d_in[0];
    const float* dec = (const float*)d_in[1];
    const float* w1  = (const float*)d_in[2];
    const float* b1  = (const float*)d_in[3];
    const float* w2  = (const float*)d_in[4];
    const float* b2  = (const float*)d_in[5];

    float* heb = (float*)d_ws;                                   // 2 MB
    unsigned short* hdb = (unsigned short*)(heb + 1024 * 512);   // 0.5 MB
    char* w2p = (char*)(hdb + 512 * 512);                        // 512 KB
    float* scF = (float*)(w2p + 512 * 1024);                     // 4 KB

    k_prep<<<64, 512, 0, stream>>>(enc, dec, w1, b1, w2, heb, hdb, w2p, scF);
    k_main<<<4096, 512, 0, stream>>>(heb, hdb, b2, w2p, scF, (float*)d_out);
}